// Round 3
// baseline (181.139 us; speedup 1.0000x reference)
//
#include <hip/hip_runtime.h>

#define BN 4096
#define KD 256
#define TILE 128
#define BK 64

typedef short bf16x8 __attribute__((ext_vector_type(8)));
typedef float f32x4 __attribute__((ext_vector_type(4)));
typedef _Float16 h2 __attribute__((ext_vector_type(2)));
typedef unsigned short ushort_t;
typedef unsigned int uint_t;

// tile slots: z=0 upper-tri 528, z=1 upper-tri 528, z=2 full 1024 -> 2080
#define NSLOT 2080

__device__ inline void async_load16(const void* g, void* l) {
    __builtin_amdgcn_global_load_lds((const __attribute__((address_space(1))) void*)g,
                                     (__attribute__((address_space(3))) void*)l,
                                     16, 0, 0);
}

__device__ inline ushort_t f2bf(float f) {
    union { float f; unsigned int u; } x;
    x.f = f;
    unsigned int u = x.u;
    unsigned int r = (u + 0x7fffu + ((u >> 16) & 1u)) >> 16;  // RTNE
    return (ushort_t)r;
}

// Kernel 0: fp32 row norms + bf16 (RTNE) copies of xs, xt. Also zeroes the
// accumulator doubles + completion counter (replaces a hipMemsetAsync).
__global__ __launch_bounds__(256) void norm_cvt(
        const float* __restrict__ xs, const float* __restrict__ xt,
        ushort_t* __restrict__ xsb, ushort_t* __restrict__ xtb,
        float* __restrict__ norms, double* __restrict__ sums,
        uint_t* __restrict__ counter) {
    if (blockIdx.x == 0) {
        if (threadIdx.x < 4) sums[threadIdx.x] = 0.0;
        if (threadIdx.x == 4) *counter = 0u;
    }
    int w = threadIdx.x >> 6;
    int lane = threadIdx.x & 63;
    int row = blockIdx.x * 4 + w;              // 0..8191
    const float* src = (row < BN) ? xs + (size_t)row * KD
                                  : xt + (size_t)(row - BN) * KD;
    ushort_t* dst = (row < BN) ? xsb + (size_t)row * KD
                               : xtb + (size_t)(row - BN) * KD;
    float4 v = ((const float4*)src)[lane];
    float s = v.x * v.x + v.y * v.y + v.z * v.z + v.w * v.w;
#pragma unroll
    for (int off = 32; off > 0; off >>= 1) s += __shfl_xor(s, off, 64);
    if (lane == 0) norms[row] = s;
    ushort4 o;
    o.x = f2bf(v.x); o.y = f2bf(v.y); o.z = f2bf(v.z); o.w = f2bf(v.w);
    ((ushort4*)dst)[lane] = o;
}

// -------- fast path: pass 1 GEMM stores d (fp16) + per-z distance sums --------

template <bool DIAG>
__device__ __forceinline__ float epilogue_store(
        const f32x4 (&acc)[4][4], const float* nxv, const float* nyv,
        int wr, int wc, int q, int m16, int tid, uint_t* __restrict__ tileBase) {
    float local = 0.0f;
#pragma unroll
    for (int rg = 0; rg < 4; ++rg) {
#pragma unroll
        for (int ng = 0; ng < 4; ++ng) {
#pragma unroll
            for (int rp = 0; rp < 2; ++rp) {
                float dpair[2];
#pragma unroll
                for (int rh = 0; rh < 2; ++rh) {
                    int rr = rp * 2 + rh;
                    float sq = nxv[rg * 4 + rr] + nyv[ng] - 2.0f * acc[rg][ng][rr];
                    sq = fmaxf(sq, 0.0f);
                    float d = sqrtf(sq);
                    if (DIAG) {
                        int i = wr * 64 + rg * 16 + q * 4 + rr;   // i0==j0 on diag tiles
                        int j = wc * 64 + ng * 16 + m16;
                        if (i == j) d = 0.0f;                     // exact-zero diagonal
                    }
                    local += d;
                    dpair[rh] = d;
                }
                h2 p;
                p[0] = (_Float16)dpair[0];
                p[1] = (_Float16)dpair[1];
                int pe = rg * 8 + ng * 2 + rp;                    // 0..31
                tileBase[pe * 256 + tid] = __builtin_bit_cast(uint_t, p);
            }
        }
    }
    return local;
}

__global__ __launch_bounds__(256) void mmd_pass1(
        const ushort_t* __restrict__ xsb, const ushort_t* __restrict__ xtb,
        const float* __restrict__ norms, double* __restrict__ sums,
        float* __restrict__ coefArr, uint_t* __restrict__ dbuf) {
    // decode slot -> (z, bi, bj)
    const int slot = blockIdx.x;
    int z, bi, bj;
    if (slot >= 1056) {
        z = 2; int t = slot - 1056; bi = t >> 5; bj = t & 31;
    } else {
        z = (slot >= 528) ? 1 : 0;
        int t = slot - z * 528;
        int b = (int)(32.5f - sqrtf(1056.25f - 2.0f * (float)t));
        while (b * (65 - b) / 2 > t) --b;
        while ((b + 1) * (64 - b) / 2 <= t) ++b;
        bi = b;
        bj = bi + (t - bi * (65 - bi) / 2);
    }

    const ushort_t* X = (z == 1) ? xtb : xsb;
    const ushort_t* Y = (z == 0) ? xsb : xtb;
    const float* nX = norms + ((z == 1) ? BN : 0);
    const float* nY = norms + ((z == 0) ? 0 : BN);

    const int tid = threadIdx.x;
    const int lane = tid & 63;
    const int w = tid >> 6;
    const int wr = w >> 1;
    const int wc = w & 1;
    const int m16 = lane & 15;
    const int q = lane >> 4;

    const int i0 = bi * TILE;
    const int j0 = bj * TILE;

    __shared__ ushort_t lA[TILE * BK];
    __shared__ ushort_t lB[TILE * BK];
    __shared__ float red[4];

    f32x4 acc[4][4] = {};

#pragma unroll
    for (int kk = 0; kk < KD; kk += BK) {
        __syncthreads();
#pragma unroll
        for (int t = 0; t < 4; ++t) {
            int rowblk = w * 4 + t;
            int r = rowblk * 8 + (lane >> 3);
            int cch = lane & 7;
            int gch = cch ^ (r & 7);
            const ushort_t* gA = X + (size_t)(i0 + r) * KD + (kk + gch * 8);
            const ushort_t* gB = Y + (size_t)(j0 + r) * KD + (kk + gch * 8);
            async_load16(gA, (char*)lA + rowblk * 1024);
            async_load16(gB, (char*)lB + rowblk * 1024);
        }
        __syncthreads();

#pragma unroll
        for (int ks = 0; ks < 2; ++ks) {
            bf16x8 af[4], bfr[4];
            int kap = ks * 4 + q;
#pragma unroll
            for (int rg = 0; rg < 4; ++rg) {
                int rowa = wr * 64 + rg * 16 + m16;
                int posa = kap ^ (rowa & 7);
                af[rg] = *(const bf16x8*)&lA[rowa * BK + posa * 8];
                int rowb = wc * 64 + rg * 16 + m16;
                int posb = kap ^ (rowb & 7);
                bfr[rg] = *(const bf16x8*)&lB[rowb * BK + posb * 8];
            }
#pragma unroll
            for (int rg = 0; rg < 4; ++rg)
#pragma unroll
                for (int ng = 0; ng < 4; ++ng)
                    acc[rg][ng] = __builtin_amdgcn_mfma_f32_16x16x32_bf16(
                        af[rg], bfr[ng], acc[rg][ng], 0, 0, 0);
        }
    }

    float nxv[16];
#pragma unroll
    for (int rg = 0; rg < 4; ++rg)
#pragma unroll
        for (int rr = 0; rr < 4; ++rr)
            nxv[rg * 4 + rr] = nX[i0 + wr * 64 + rg * 16 + q * 4 + rr];
    float nyv[4];
#pragma unroll
    for (int ng = 0; ng < 4; ++ng)
        nyv[ng] = nY[j0 + wc * 64 + ng * 16 + m16];

    uint_t* tileBase = dbuf + (size_t)slot * 8192;
    float local;
    if (z < 2 && bi == bj)
        local = epilogue_store<true>(acc, nxv, nyv, wr, wc, q, m16, tid, tileBase);
    else
        local = epilogue_store<false>(acc, nxv, nyv, wr, wc, q, m16, tid, tileBase);

#pragma unroll
    for (int off = 32; off > 0; off >>= 1) local += __shfl_xor(local, off, 64);
    if (lane == 0) red[w] = local;
    __syncthreads();
    if (tid == 0) {
        double bs = (double)red[0] + (double)red[1] + (double)red[2] + (double)red[3];
        double c1 = (z < 2 && bi != bj) ? 2.0 : 1.0;   // pass-1 (mean) coefficient
        atomicAdd(&sums[z], c1 * bs);
        // pass-2 coefficient for this tile
        float c2 = (z == 2) ? -2.0f : ((bi != bj) ? 2.0f : 1.0f);
        coefArr[slot] = c2;
    }
}

// -------- fast path: pass 2 elementwise exp-sum over stored d, inline finalize --------

__global__ __launch_bounds__(256) void mmd_pass2(
        const uint_t* __restrict__ dbuf, const float* __restrict__ coefArr,
        double* __restrict__ sums, uint_t* __restrict__ counter,
        float* __restrict__ out) {
    const int tid = threadIdx.x;
    const int slot = blockIdx.x;
    const int lane = tid & 63;
    const int w = tid >> 6;
    int z = (slot < 528) ? 0 : (slot < 1056) ? 1 : 2;
    double mz = sums[z] * (1.0 / 16777216.0);     // mean over 4096^2
    float nhb = (float)(-1.4426950408889634 / (4.0 * mz));  // alpha=2 exponent scale
    float coef = coefArr[slot];
    const uint_t* base = dbuf + (size_t)slot * 8192;

    float local = 0.0f;
#pragma unroll
    for (int it = 0; it < 8; ++it) {
        uint4 v = ((const uint4*)base)[it * 256 + tid];
        uint_t arr[4] = {v.x, v.y, v.z, v.w};
#pragma unroll
        for (int j = 0; j < 4; ++j) {
            h2 p = __builtin_bit_cast(h2, arr[j]);
#pragma unroll
            for (int h = 0; h < 2; ++h) {
                float d = (float)p[h];
                // sum over alphas {1/8,1/4,1/2,1,2}: u^16+u^8+u^4+u^2+u, u=2^(d*nhb)
                float u = exp2f(d * nhb);
                float u2 = u * u;
                float u4 = u2 * u2;
                float u8 = u4 * u4;
                float u16 = u8 * u8;
                local += (u + u2) + (u4 + u8) + u16;
            }
        }
    }

    __shared__ float red[4];
    __shared__ bool amLast;
#pragma unroll
    for (int off = 32; off > 0; off >>= 1) local += __shfl_xor(local, off, 64);
    if (lane == 0) red[w] = local;
    __syncthreads();
    if (tid == 0) {
        double bs = (double)red[0] + (double)red[1] + (double)red[2] + (double)red[3];
        atomicAdd(&sums[3], (double)coef * bs);
        __threadfence();
        uint_t c = atomicAdd(counter, 1u);
        amLast = (c == (uint_t)gridDim.x - 1u);
    }
    __syncthreads();
    if (tid == 0 && amLast) {
        double S = atomicAdd(&sums[3], 0.0);   // atomic read-back (coherent)
        double l = sqrt(S / ((double)BN * (double)(BN - 1)));
        float f = (float)l;
        if (!(f == f)) f = 0.0f;
        out[0] = f;
    }
}

// -------- fallback path (ws too small for the d-buffer): round-1 two-GEMM --------

template <int PASS>
__global__ __launch_bounds__(256) void mmd_gemm(
        const ushort_t* __restrict__ xsb, const ushort_t* __restrict__ xtb,
        const float* __restrict__ norms, double* __restrict__ sums) {
    const int z = blockIdx.z;
    const int bi = blockIdx.y;
    const int bj = blockIdx.x;
    if (z < 2 && bj < bi) return;

    const ushort_t* X = (z == 1) ? xtb : xsb;
    const ushort_t* Y = (z == 0) ? xsb : xtb;
    const float* nX = norms + ((z == 1) ? BN : 0);
    const float* nY = norms + ((z == 0) ? 0 : BN);

    const int tid = threadIdx.x;
    const int lane = tid & 63;
    const int w = tid >> 6;
    const int wr = w >> 1;
    const int wc = w & 1;
    const int m16 = lane & 15;
    const int q = lane >> 4;

    const int i0 = bi * TILE;
    const int j0 = bj * TILE;

    __shared__ ushort_t lA[TILE * BK];
    __shared__ ushort_t lB[TILE * BK];
    __shared__ float red[4];

    float nhb = 0.0f;
    if (PASS == 2) {
        double mz = sums[z] / ((double)BN * (double)BN);
        nhb = (float)(-1.4426950408889634 / (4.0 * mz));
    }

    f32x4 acc[4][4] = {};

#pragma unroll
    for (int kk = 0; kk < KD; kk += BK) {
        __syncthreads();
#pragma unroll
        for (int t = 0; t < 4; ++t) {
            int rowblk = w * 4 + t;
            int r = rowblk * 8 + (lane >> 3);
            int cch = lane & 7;
            int gch = cch ^ (r & 7);
            const ushort_t* gA = X + (size_t)(i0 + r) * KD + (kk + gch * 8);
            const ushort_t* gB = Y + (size_t)(j0 + r) * KD + (kk + gch * 8);
            async_load16(gA, (char*)lA + rowblk * 1024);
            async_load16(gB, (char*)lB + rowblk * 1024);
        }
        __syncthreads();

#pragma unroll
        for (int ks = 0; ks < 2; ++ks) {
            bf16x8 af[4], bfr[4];
            int kap = ks * 4 + q;
#pragma unroll
            for (int rg = 0; rg < 4; ++rg) {
                int rowa = wr * 64 + rg * 16 + m16;
                int posa = kap ^ (rowa & 7);
                af[rg] = *(const bf16x8*)&lA[rowa * BK + posa * 8];
                int rowb = wc * 64 + rg * 16 + m16;
                int posb = kap ^ (rowb & 7);
                bfr[rg] = *(const bf16x8*)&lB[rowb * BK + posb * 8];
            }
#pragma unroll
            for (int rg = 0; rg < 4; ++rg)
#pragma unroll
                for (int ng = 0; ng < 4; ++ng)
                    acc[rg][ng] = __builtin_amdgcn_mfma_f32_16x16x32_bf16(
                        af[rg], bfr[ng], acc[rg][ng], 0, 0, 0);
        }
    }

    float nxv[16];
#pragma unroll
    for (int rg = 0; rg < 4; ++rg)
#pragma unroll
        for (int rr = 0; rr < 4; ++rr)
            nxv[rg * 4 + rr] = nX[i0 + wr * 64 + rg * 16 + q * 4 + rr];
    float nyv[4];
#pragma unroll
    for (int ng = 0; ng < 4; ++ng)
        nyv[ng] = nY[j0 + wc * 64 + ng * 16 + m16];

    float local = 0.0f;
#pragma unroll
    for (int rg = 0; rg < 4; ++rg) {
#pragma unroll
        for (int ng = 0; ng < 4; ++ng) {
#pragma unroll
            for (int rr = 0; rr < 4; ++rr) {
                int i = i0 + wr * 64 + rg * 16 + q * 4 + rr;
                int j = j0 + wc * 64 + ng * 16 + m16;
                float sq = nxv[rg * 4 + rr] + nyv[ng] - 2.0f * acc[rg][ng][rr];
                sq = fmaxf(sq, 0.0f);
                float d = sqrtf(sq);
                if (z < 2 && i == j) d = 0.0f;
                if (PASS == 1) {
                    local += d;
                } else {
                    float u = exp2f(d * nhb);
                    float u2 = u * u;
                    float u4 = u2 * u2;
                    float u8 = u4 * u4;
                    float u16 = u8 * u8;
                    local += u + u2 + u4 + u8 + u16;
                }
            }
        }
    }

#pragma unroll
    for (int off = 32; off > 0; off >>= 1) local += __shfl_xor(local, off, 64);
    if (lane == 0) red[w] = local;
    __syncthreads();
    if (tid == 0) {
        double bs = (double)red[0] + (double)red[1] + (double)red[2] + (double)red[3];
        double coef = (z < 2 && bi != bj) ? 2.0 : 1.0;
        if (PASS == 2 && z == 2) coef = -2.0;
        atomicAdd(&sums[PASS == 1 ? z : 3], coef * bs);
    }
}

__global__ void mmd_finalize(const double* __restrict__ sums, float* __restrict__ out) {
    double S = sums[3];
    double l = sqrt(S / ((double)BN * (double)(BN - 1)));
    float f = (float)l;
    if (!(f == f)) f = 0.0f;
    out[0] = f;
}

extern "C" void kernel_launch(void* const* d_in, const int* in_sizes, int n_in,
                              void* d_out, int out_size, void* d_ws, size_t ws_size,
                              hipStream_t stream) {
    const float* xs = (const float*)d_in[0];
    const float* xt = (const float*)d_in[1];
    float* out = (float*)d_out;

    char* ws = (char*)d_ws;
    double* sums = (double*)ws;                    // 4 doubles @ 0
    uint_t* counter = (uint_t*)(ws + 32);          // 1 uint  @ 32 (pad to 64)
    float* norms = (float*)(ws + 64);              // 8192 floats -> ends at 32832
    float* coefArr = (float*)(ws + 32832);         // 2080 floats -> ends 41152 (pad 41216)
    ushort_t* xsb = (ushort_t*)(ws + 41216);       // 2 MB
    ushort_t* xtb = xsb + (size_t)BN * KD;         // 2 MB -> ends at 4235520
    uint_t* dbuf = (uint_t*)(ws + 4235520);        // 2080*32768 B = 68.16 MB

    size_t need_small = 4235520;
    size_t need_big = 4235520 + (size_t)NSLOT * 32768;

    if (ws_size < need_small) {
        (void)hipMemsetAsync(d_out, 0xC0, 4, stream);    // diagnostic marker
        return;
    }

    norm_cvt<<<2048, 256, 0, stream>>>(xs, xt, xsb, xtb, norms, sums, counter);

    if (ws_size >= need_big) {
        mmd_pass1<<<NSLOT, 256, 0, stream>>>(xsb, xtb, norms, sums, coefArr, dbuf);
        mmd_pass2<<<NSLOT, 256, 0, stream>>>(dbuf, coefArr, sums, counter, out);
    } else {
        dim3 g(32, 32, 3);
        mmd_gemm<1><<<g, 256, 0, stream>>>(xsb, xtb, norms, sums);
        mmd_gemm<2><<<g, 256, 0, stream>>>(xsb, xtb, norms, sums);
        mmd_finalize<<<1, 1, 0, stream>>>(sums, out);
    }
}

// Round 4
// 132.338 us; speedup vs baseline: 1.3688x; 1.3688x over previous
//
#include <hip/hip_runtime.h>

#define BN 4096
#define KD 256
#define TILE 128
#define BK 64

typedef short bf16x8 __attribute__((ext_vector_type(8)));
typedef float f32x4 __attribute__((ext_vector_type(4)));
typedef _Float16 h2 __attribute__((ext_vector_type(2)));
typedef unsigned short ushort_t;
typedef unsigned int uint_t;

// tile slots: z=0 upper-tri 528, z=1 upper-tri 528, z=2 full 1024 -> 2080
#define NSLOT 2080

__device__ inline void async_load16(const void* g, void* l) {
    __builtin_amdgcn_global_load_lds((const __attribute__((address_space(1))) void*)g,
                                     (__attribute__((address_space(3))) void*)l,
                                     16, 0, 0);
}

__device__ inline ushort_t f2bf(float f) {
    union { float f; unsigned int u; } x;
    x.f = f;
    unsigned int u = x.u;
    unsigned int r = (u + 0x7fffu + ((u >> 16) & 1u)) >> 16;  // RTNE
    return (ushort_t)r;
}

__device__ __forceinline__ void decode_slot(int slot, int& z, int& bi, int& bj) {
    if (slot >= 1056) {
        z = 2; int t = slot - 1056; bi = t >> 5; bj = t & 31;
    } else {
        z = (slot >= 528) ? 1 : 0;
        int t = slot - z * 528;
        int b = (int)(32.5f - sqrtf(1056.25f - 2.0f * (float)t));
        while (b * (65 - b) / 2 > t) --b;
        while ((b + 1) * (64 - b) / 2 <= t) ++b;
        bi = b;
        bj = bi + (t - bi * (65 - bi) / 2);
    }
}

// Kernel 0: fp32 row norms + bf16 (RTNE) copies of xs, xt.
__global__ __launch_bounds__(256) void norm_cvt(
        const float* __restrict__ xs, const float* __restrict__ xt,
        ushort_t* __restrict__ xsb, ushort_t* __restrict__ xtb,
        float* __restrict__ norms) {
    int w = threadIdx.x >> 6;
    int lane = threadIdx.x & 63;
    int row = blockIdx.x * 4 + w;              // 0..8191
    const float* src = (row < BN) ? xs + (size_t)row * KD
                                  : xt + (size_t)(row - BN) * KD;
    ushort_t* dst = (row < BN) ? xsb + (size_t)row * KD
                               : xtb + (size_t)(row - BN) * KD;
    float4 v = ((const float4*)src)[lane];
    float s = v.x * v.x + v.y * v.y + v.z * v.z + v.w * v.w;
#pragma unroll
    for (int off = 32; off > 0; off >>= 1) s += __shfl_xor(s, off, 64);
    if (lane == 0) norms[row] = s;
    ushort4 o;
    o.x = f2bf(v.x); o.y = f2bf(v.y); o.z = f2bf(v.z); o.w = f2bf(v.w);
    ((ushort4*)dst)[lane] = o;
}

// -------- pass 1: GEMM -> d (fp16) to dbuf + per-tile distance partial (no atomics) ----

template <bool DIAG>
__device__ __forceinline__ float epilogue_store(
        const f32x4 (&acc)[4][4], const float* nxv, const float* nyv,
        int wr, int wc, int q, int m16, int tid, uint_t* __restrict__ tileBase) {
    float local = 0.0f;
#pragma unroll
    for (int rg = 0; rg < 4; ++rg) {
#pragma unroll
        for (int ng = 0; ng < 4; ++ng) {
#pragma unroll
            for (int rp = 0; rp < 2; ++rp) {
                float dpair[2];
#pragma unroll
                for (int rh = 0; rh < 2; ++rh) {
                    int rr = rp * 2 + rh;
                    float sq = nxv[rg * 4 + rr] + nyv[ng] - 2.0f * acc[rg][ng][rr];
                    sq = fmaxf(sq, 0.0f);
                    float d = sqrtf(sq);
                    if (DIAG) {
                        int i = wr * 64 + rg * 16 + q * 4 + rr;   // i0==j0 on diag tiles
                        int j = wc * 64 + ng * 16 + m16;
                        if (i == j) d = 0.0f;                     // exact-zero diagonal
                    }
                    local += d;
                    dpair[rh] = d;
                }
                h2 p;
                p[0] = (_Float16)dpair[0];
                p[1] = (_Float16)dpair[1];
                int pe = rg * 8 + ng * 2 + rp;                    // 0..31
                tileBase[pe * 256 + tid] = __builtin_bit_cast(uint_t, p);
            }
        }
    }
    return local;
}

__global__ __launch_bounds__(256) void mmd_pass1(
        const ushort_t* __restrict__ xsb, const ushort_t* __restrict__ xtb,
        const float* __restrict__ norms, float* __restrict__ partialArr,
        uint_t* __restrict__ dbuf) {
    const int slot = blockIdx.x;
    int z, bi, bj;
    decode_slot(slot, z, bi, bj);

    const ushort_t* X = (z == 1) ? xtb : xsb;
    const ushort_t* Y = (z == 0) ? xsb : xtb;
    const float* nX = norms + ((z == 1) ? BN : 0);
    const float* nY = norms + ((z == 0) ? 0 : BN);

    const int tid = threadIdx.x;
    const int lane = tid & 63;
    const int w = tid >> 6;
    const int wr = w >> 1;
    const int wc = w & 1;
    const int m16 = lane & 15;
    const int q = lane >> 4;

    const int i0 = bi * TILE;
    const int j0 = bj * TILE;

    __shared__ ushort_t lA[TILE * BK];
    __shared__ ushort_t lB[TILE * BK];
    __shared__ float red[4];

    f32x4 acc[4][4] = {};

#pragma unroll
    for (int kk = 0; kk < KD; kk += BK) {
        __syncthreads();
#pragma unroll
        for (int t = 0; t < 4; ++t) {
            int rowblk = w * 4 + t;
            int r = rowblk * 8 + (lane >> 3);
            int cch = lane & 7;
            int gch = cch ^ (r & 7);
            const ushort_t* gA = X + (size_t)(i0 + r) * KD + (kk + gch * 8);
            const ushort_t* gB = Y + (size_t)(j0 + r) * KD + (kk + gch * 8);
            async_load16(gA, (char*)lA + rowblk * 1024);
            async_load16(gB, (char*)lB + rowblk * 1024);
        }
        __syncthreads();

#pragma unroll
        for (int ks = 0; ks < 2; ++ks) {
            bf16x8 af[4], bfr[4];
            int kap = ks * 4 + q;
#pragma unroll
            for (int rg = 0; rg < 4; ++rg) {
                int rowa = wr * 64 + rg * 16 + m16;
                int posa = kap ^ (rowa & 7);
                af[rg] = *(const bf16x8*)&lA[rowa * BK + posa * 8];
                int rowb = wc * 64 + rg * 16 + m16;
                int posb = kap ^ (rowb & 7);
                bfr[rg] = *(const bf16x8*)&lB[rowb * BK + posb * 8];
            }
#pragma unroll
            for (int rg = 0; rg < 4; ++rg)
#pragma unroll
                for (int ng = 0; ng < 4; ++ng)
                    acc[rg][ng] = __builtin_amdgcn_mfma_f32_16x16x32_bf16(
                        af[rg], bfr[ng], acc[rg][ng], 0, 0, 0);
        }
    }

    float nxv[16];
#pragma unroll
    for (int rg = 0; rg < 4; ++rg)
#pragma unroll
        for (int rr = 0; rr < 4; ++rr)
            nxv[rg * 4 + rr] = nX[i0 + wr * 64 + rg * 16 + q * 4 + rr];
    float nyv[4];
#pragma unroll
    for (int ng = 0; ng < 4; ++ng)
        nyv[ng] = nY[j0 + wc * 64 + ng * 16 + m16];

    uint_t* tileBase = dbuf + (size_t)slot * 8192;
    float local;
    if (z < 2 && bi == bj)
        local = epilogue_store<true>(acc, nxv, nyv, wr, wc, q, m16, tid, tileBase);
    else
        local = epilogue_store<false>(acc, nxv, nyv, wr, wc, q, m16, tid, tileBase);

#pragma unroll
    for (int off = 32; off > 0; off >>= 1) local += __shfl_xor(local, off, 64);
    if (lane == 0) red[w] = local;
    __syncthreads();
    if (tid == 0) {
        float bs = red[0] + red[1] + red[2] + red[3];
        float c1 = (z < 2 && bi != bj) ? 2.0f : 1.0f;    // mean coefficient
        partialArr[slot] = c1 * bs;                       // plain store, no atomic
    }
}

// -------- reduce1: per-z distance sums from tile partials (1 block) --------

__global__ __launch_bounds__(256) void mmd_reduce1(
        const float* __restrict__ partialArr, double* __restrict__ sums) {
    const int tid = threadIdx.x;
    double a0 = 0.0, a1 = 0.0, a2 = 0.0;
    for (int s = tid; s < NSLOT; s += 256) {
        double v = (double)partialArr[s];
        if (s < 528) a0 += v; else if (s < 1056) a1 += v; else a2 += v;
    }
    const int lane = tid & 63, w = tid >> 6;
#pragma unroll
    for (int off = 32; off > 0; off >>= 1) {
        a0 += __shfl_xor(a0, off, 64);
        a1 += __shfl_xor(a1, off, 64);
        a2 += __shfl_xor(a2, off, 64);
    }
    __shared__ double r[4][3];
    if (lane == 0) { r[w][0] = a0; r[w][1] = a1; r[w][2] = a2; }
    __syncthreads();
    if (tid == 0) {
        sums[0] = r[0][0] + r[1][0] + r[2][0] + r[3][0];
        sums[1] = r[0][1] + r[1][1] + r[2][1] + r[3][1];
        sums[2] = r[0][2] + r[1][2] + r[2][2] + r[3][2];
    }
}

// -------- pass 2: elementwise exp-sum over stored d -> tile partial (no atomics) ------

__global__ __launch_bounds__(256) void mmd_pass2(
        const uint_t* __restrict__ dbuf, const double* __restrict__ sums,
        float* __restrict__ partialArr) {
    const int tid = threadIdx.x;
    const int slot = blockIdx.x;
    const int lane = tid & 63;
    const int w = tid >> 6;
    int z, bi, bj;
    decode_slot(slot, z, bi, bj);
    double mz = sums[z] * (1.0 / 16777216.0);     // mean over 4096^2
    float nhb = (float)(-1.4426950408889634 / (4.0 * mz));  // alpha=2 exponent scale
    float coef = (z == 2) ? -2.0f : ((bi != bj) ? 2.0f : 1.0f);
    const uint_t* base = dbuf + (size_t)slot * 8192;

    float local = 0.0f;
#pragma unroll
    for (int it = 0; it < 8; ++it) {
        uint4 v = ((const uint4*)base)[it * 256 + tid];
        uint_t arr[4] = {v.x, v.y, v.z, v.w};
#pragma unroll
        for (int j = 0; j < 4; ++j) {
            h2 p = __builtin_bit_cast(h2, arr[j]);
#pragma unroll
            for (int h = 0; h < 2; ++h) {
                float d = (float)p[h];
                // sum over alphas {1/8,1/4,1/2,1,2}: u^16+u^8+u^4+u^2+u, u=2^(d*nhb)
                float u = exp2f(d * nhb);
                float u2 = u * u;
                float u4 = u2 * u2;
                float u8 = u4 * u4;
                float u16 = u8 * u8;
                local += (u + u2) + (u4 + u8) + u16;
            }
        }
    }

    __shared__ float red[4];
#pragma unroll
    for (int off = 32; off > 0; off >>= 1) local += __shfl_xor(local, off, 64);
    if (lane == 0) red[w] = local;
    __syncthreads();
    if (tid == 0) {
        float bs = red[0] + red[1] + red[2] + red[3];
        partialArr[slot] = coef * bs;                     // plain store, no atomic
    }
}

// -------- finalize: reduce tile partials -> loss (1 block) --------

__global__ __launch_bounds__(256) void mmd_finalize2(
        const float* __restrict__ partialArr, float* __restrict__ out) {
    const int tid = threadIdx.x;
    double acc = 0.0;
    for (int s = tid; s < NSLOT; s += 256) acc += (double)partialArr[s];
    const int lane = tid & 63, w = tid >> 6;
#pragma unroll
    for (int off = 32; off > 0; off >>= 1) acc += __shfl_xor(acc, off, 64);
    __shared__ double r[4];
    if (lane == 0) r[w] = acc;
    __syncthreads();
    if (tid == 0) {
        double S = r[0] + r[1] + r[2] + r[3];
        double l = sqrt(S / ((double)BN * (double)(BN - 1)));
        float f = (float)l;
        if (!(f == f)) f = 0.0f;
        out[0] = f;
    }
}

// -------- fallback path (ws too small for the d-buffer): two-GEMM w/ atomics --------

template <int PASS>
__global__ __launch_bounds__(256) void mmd_gemm(
        const ushort_t* __restrict__ xsb, const ushort_t* __restrict__ xtb,
        const float* __restrict__ norms, double* __restrict__ sums) {
    const int z = blockIdx.z;
    const int bi = blockIdx.y;
    const int bj = blockIdx.x;
    if (z < 2 && bj < bi) return;

    const ushort_t* X = (z == 1) ? xtb : xsb;
    const ushort_t* Y = (z == 0) ? xsb : xtb;
    const float* nX = norms + ((z == 1) ? BN : 0);
    const float* nY = norms + ((z == 0) ? 0 : BN);

    const int tid = threadIdx.x;
    const int lane = tid & 63;
    const int w = tid >> 6;
    const int wr = w >> 1;
    const int wc = w & 1;
    const int m16 = lane & 15;
    const int q = lane >> 4;

    const int i0 = bi * TILE;
    const int j0 = bj * TILE;

    __shared__ ushort_t lA[TILE * BK];
    __shared__ ushort_t lB[TILE * BK];
    __shared__ float red[4];

    float nhb = 0.0f;
    if (PASS == 2) {
        double mz = sums[z] / ((double)BN * (double)BN);
        nhb = (float)(-1.4426950408889634 / (4.0 * mz));
    }

    f32x4 acc[4][4] = {};

#pragma unroll
    for (int kk = 0; kk < KD; kk += BK) {
        __syncthreads();
#pragma unroll
        for (int t = 0; t < 4; ++t) {
            int rowblk = w * 4 + t;
            int r = rowblk * 8 + (lane >> 3);
            int cch = lane & 7;
            int gch = cch ^ (r & 7);
            const ushort_t* gA = X + (size_t)(i0 + r) * KD + (kk + gch * 8);
            const ushort_t* gB = Y + (size_t)(j0 + r) * KD + (kk + gch * 8);
            async_load16(gA, (char*)lA + rowblk * 1024);
            async_load16(gB, (char*)lB + rowblk * 1024);
        }
        __syncthreads();

#pragma unroll
        for (int ks = 0; ks < 2; ++ks) {
            bf16x8 af[4], bfr[4];
            int kap = ks * 4 + q;
#pragma unroll
            for (int rg = 0; rg < 4; ++rg) {
                int rowa = wr * 64 + rg * 16 + m16;
                int posa = kap ^ (rowa & 7);
                af[rg] = *(const bf16x8*)&lA[rowa * BK + posa * 8];
                int rowb = wc * 64 + rg * 16 + m16;
                int posb = kap ^ (rowb & 7);
                bfr[rg] = *(const bf16x8*)&lB[rowb * BK + posb * 8];
            }
#pragma unroll
            for (int rg = 0; rg < 4; ++rg)
#pragma unroll
                for (int ng = 0; ng < 4; ++ng)
                    acc[rg][ng] = __builtin_amdgcn_mfma_f32_16x16x32_bf16(
                        af[rg], bfr[ng], acc[rg][ng], 0, 0, 0);
        }
    }

    float nxv[16];
#pragma unroll
    for (int rg = 0; rg < 4; ++rg)
#pragma unroll
        for (int rr = 0; rr < 4; ++rr)
            nxv[rg * 4 + rr] = nX[i0 + wr * 64 + rg * 16 + q * 4 + rr];
    float nyv[4];
#pragma unroll
    for (int ng = 0; ng < 4; ++ng)
        nyv[ng] = nY[j0 + wc * 64 + ng * 16 + m16];

    float local = 0.0f;
#pragma unroll
    for (int rg = 0; rg < 4; ++rg) {
#pragma unroll
        for (int ng = 0; ng < 4; ++ng) {
#pragma unroll
            for (int rr = 0; rr < 4; ++rr) {
                int i = i0 + wr * 64 + rg * 16 + q * 4 + rr;
                int j = j0 + wc * 64 + ng * 16 + m16;
                float sq = nxv[rg * 4 + rr] + nyv[ng] - 2.0f * acc[rg][ng][rr];
                sq = fmaxf(sq, 0.0f);
                float d = sqrtf(sq);
                if (z < 2 && i == j) d = 0.0f;
                if (PASS == 1) {
                    local += d;
                } else {
                    float u = exp2f(d * nhb);
                    float u2 = u * u;
                    float u4 = u2 * u2;
                    float u8 = u4 * u4;
                    float u16 = u8 * u8;
                    local += u + u2 + u4 + u8 + u16;
                }
            }
        }
    }

#pragma unroll
    for (int off = 32; off > 0; off >>= 1) local += __shfl_xor(local, off, 64);
    if (lane == 0) red[w] = local;
    __syncthreads();
    if (tid == 0) {
        double bs = (double)red[0] + (double)red[1] + (double)red[2] + (double)red[3];
        double coef = (z < 2 && bi != bj) ? 2.0 : 1.0;
        if (PASS == 2 && z == 2) coef = -2.0;
        atomicAdd(&sums[PASS == 1 ? z : 3], coef * bs);
    }
}

__global__ void mmd_finalize(const double* __restrict__ sums, float* __restrict__ out) {
    double S = sums[3];
    double l = sqrt(S / ((double)BN * (double)(BN - 1)));
    float f = (float)l;
    if (!(f == f)) f = 0.0f;
    out[0] = f;
}

extern "C" void kernel_launch(void* const* d_in, const int* in_sizes, int n_in,
                              void* d_out, int out_size, void* d_ws, size_t ws_size,
                              hipStream_t stream) {
    const float* xs = (const float*)d_in[0];
    const float* xt = (const float*)d_in[1];
    float* out = (float*)d_out;

    char* ws = (char*)d_ws;
    double* sums = (double*)ws;                    // 4 doubles @ 0
    float* norms = (float*)(ws + 64);              // 8192 floats -> ends 32832
    float* partialArr = (float*)(ws + 32832);      // 2080 floats -> ends 41152 (pad 41216)
    ushort_t* xsb = (ushort_t*)(ws + 41216);       // 2 MB
    ushort_t* xtb = xsb + (size_t)BN * KD;         // 2 MB -> ends at 4235520
    uint_t* dbuf = (uint_t*)(ws + 4235520);        // 2080*32768 B = 68.16 MB

    size_t need_small = 4235520;
    size_t need_big = 4235520 + (size_t)NSLOT * 32768;   // 72,392,960 (same as round 3)

    if (ws_size < need_small) {
        (void)hipMemsetAsync(d_out, 0xC0, 4, stream);    // diagnostic marker
        return;
    }

    norm_cvt<<<2048, 256, 0, stream>>>(xs, xt, xsb, xtb, norms);

    if (ws_size >= need_big) {
        mmd_pass1<<<NSLOT, 256, 0, stream>>>(xsb, xtb, norms, partialArr, dbuf);
        mmd_reduce1<<<1, 256, 0, stream>>>(partialArr, sums);
        mmd_pass2<<<NSLOT, 256, 0, stream>>>(dbuf, sums, partialArr);
        mmd_finalize2<<<1, 256, 0, stream>>>(partialArr, out);
    } else {
        (void)hipMemsetAsync(d_ws, 0, 64, stream);
        dim3 g(32, 32, 3);
        mmd_gemm<1><<<g, 256, 0, stream>>>(xsb, xtb, norms, sums);
        mmd_gemm<2><<<g, 256, 0, stream>>>(xsb, xtb, norms, sums);
        mmd_finalize<<<1, 1, 0, stream>>>(sums, out);
    }
}

// Round 5
// 116.147 us; speedup vs baseline: 1.5596x; 1.1394x over previous
//
#include <hip/hip_runtime.h>

#define BN 4096
#define KD 256
#define TILE 128
#define BK 64

typedef short bf16x8 __attribute__((ext_vector_type(8)));
typedef float f32x4 __attribute__((ext_vector_type(4)));
typedef _Float16 h2 __attribute__((ext_vector_type(2)));
typedef unsigned short ushort_t;
typedef unsigned int uint_t;

// tile slots: z=0 upper-tri 528, z=1 upper-tri 528, z=2 full 1024 -> 2080
#define NSLOT 2080

__device__ inline void async_load16(const void* g, void* l) {
    __builtin_amdgcn_global_load_lds((const __attribute__((address_space(1))) void*)g,
                                     (__attribute__((address_space(3))) void*)l,
                                     16, 0, 0);
}

__device__ inline ushort_t f2bf(float f) {
    union { float f; unsigned int u; } x;
    x.f = f;
    unsigned int u = x.u;
    unsigned int r = (u + 0x7fffu + ((u >> 16) & 1u)) >> 16;  // RTNE
    return (ushort_t)r;
}

__device__ __forceinline__ float fast_sqrt(float x) {
    return __builtin_amdgcn_sqrtf(x);     // v_sqrt_f32, ~1 ulp — enough for fp16 storage
}
__device__ __forceinline__ float fast_exp2(float x) {
    return __builtin_amdgcn_exp2f(x);     // v_exp_f32, no ocml fixup path
}

__device__ __forceinline__ void decode_slot(int slot, int& z, int& bi, int& bj) {
    if (slot >= 1056) {
        z = 2; int t = slot - 1056; bi = t >> 5; bj = t & 31;
    } else {
        z = (slot >= 528) ? 1 : 0;
        int t = slot - z * 528;
        int b = (int)(32.5f - sqrtf(1056.25f - 2.0f * (float)t));
        while (b * (65 - b) / 2 > t) --b;
        while ((b + 1) * (64 - b) / 2 <= t) ++b;
        bi = b;
        bj = bi + (t - bi * (65 - bi) / 2);
    }
}

// Kernel 0: fp32 row norms + bf16 (RTNE) copies of xs, xt.
__global__ __launch_bounds__(256) void norm_cvt(
        const float* __restrict__ xs, const float* __restrict__ xt,
        ushort_t* __restrict__ xsb, ushort_t* __restrict__ xtb,
        float* __restrict__ norms) {
    int w = threadIdx.x >> 6;
    int lane = threadIdx.x & 63;
    int row = blockIdx.x * 4 + w;              // 0..8191
    const float* src = (row < BN) ? xs + (size_t)row * KD
                                  : xt + (size_t)(row - BN) * KD;
    ushort_t* dst = (row < BN) ? xsb + (size_t)row * KD
                               : xtb + (size_t)(row - BN) * KD;
    float4 v = ((const float4*)src)[lane];
    float s = v.x * v.x + v.y * v.y + v.z * v.z + v.w * v.w;
#pragma unroll
    for (int off = 32; off > 0; off >>= 1) s += __shfl_xor(s, off, 64);
    if (lane == 0) norms[row] = s;
    ushort4 o;
    o.x = f2bf(v.x); o.y = f2bf(v.y); o.z = f2bf(v.z); o.w = f2bf(v.w);
    ((ushort4*)dst)[lane] = o;
}

// -------- pass 1: GEMM -> d (fp16, 16B-packed) to dbuf + per-tile partial --------

template <bool DIAG>
__device__ __forceinline__ float epilogue_store(
        const f32x4 (&acc)[4][4], const float* nxv, const float* nyv,
        int wr, int wc, int q, int m16, int tid, uint_t* __restrict__ tileBase) {
    float local = 0.0f;
    uint4* tb4 = (uint4*)tileBase;
#pragma unroll
    for (int rg = 0; rg < 4; ++rg) {
#pragma unroll
        for (int np = 0; np < 2; ++np) {          // pair of ng's -> one uint4
            uint_t packed[4];
#pragma unroll
            for (int ngh = 0; ngh < 2; ++ngh) {
                int ng = np * 2 + ngh;
#pragma unroll
                for (int rp = 0; rp < 2; ++rp) {
                    float dpair[2];
#pragma unroll
                    for (int rh = 0; rh < 2; ++rh) {
                        int rr = rp * 2 + rh;
                        float sq = nxv[rg * 4 + rr] + nyv[ng] - 2.0f * acc[rg][ng][rr];
                        sq = fmaxf(sq, 0.0f);
                        float d = fast_sqrt(sq);
                        if (DIAG) {
                            int i = wr * 64 + rg * 16 + q * 4 + rr;  // i0==j0 on diag
                            int j = wc * 64 + ng * 16 + m16;
                            if (i == j) d = 0.0f;                    // exact-zero diag
                        }
                        local += d;
                        dpair[rh] = d;
                    }
                    h2 p;
                    p[0] = (_Float16)dpair[0];
                    p[1] = (_Float16)dpair[1];
                    packed[ngh * 2 + rp] = __builtin_bit_cast(uint_t, p);
                }
            }
            uint4 v;
            v.x = packed[0]; v.y = packed[1]; v.z = packed[2]; v.w = packed[3];
            tb4[(rg * 2 + np) * 256 + tid] = v;   // one dwordx4 store
        }
    }
    return local;
}

__global__ __launch_bounds__(256) void mmd_pass1(
        const ushort_t* __restrict__ xsb, const ushort_t* __restrict__ xtb,
        const float* __restrict__ norms, float* __restrict__ partialArr,
        uint_t* __restrict__ dbuf) {
    const int slot = blockIdx.x;
    int z, bi, bj;
    decode_slot(slot, z, bi, bj);

    const ushort_t* X = (z == 1) ? xtb : xsb;
    const ushort_t* Y = (z == 0) ? xsb : xtb;
    const float* nX = norms + ((z == 1) ? BN : 0);
    const float* nY = norms + ((z == 0) ? 0 : BN);

    const int tid = threadIdx.x;
    const int lane = tid & 63;
    const int w = tid >> 6;
    const int wr = w >> 1;
    const int wc = w & 1;
    const int m16 = lane & 15;
    const int q = lane >> 4;

    const int i0 = bi * TILE;
    const int j0 = bj * TILE;

    __shared__ ushort_t lA[TILE * BK];
    __shared__ ushort_t lB[TILE * BK];
    __shared__ float red[4];

    f32x4 acc[4][4] = {};

#pragma unroll
    for (int kk = 0; kk < KD; kk += BK) {
        __syncthreads();
#pragma unroll
        for (int t = 0; t < 4; ++t) {
            int rowblk = w * 4 + t;
            int r = rowblk * 8 + (lane >> 3);
            int cch = lane & 7;
            int gch = cch ^ (r & 7);
            const ushort_t* gA = X + (size_t)(i0 + r) * KD + (kk + gch * 8);
            const ushort_t* gB = Y + (size_t)(j0 + r) * KD + (kk + gch * 8);
            async_load16(gA, (char*)lA + rowblk * 1024);
            async_load16(gB, (char*)lB + rowblk * 1024);
        }
        __syncthreads();

#pragma unroll
        for (int ks = 0; ks < 2; ++ks) {
            bf16x8 af[4], bfr[4];
            int kap = ks * 4 + q;
#pragma unroll
            for (int rg = 0; rg < 4; ++rg) {
                int rowa = wr * 64 + rg * 16 + m16;
                int posa = kap ^ (rowa & 7);
                af[rg] = *(const bf16x8*)&lA[rowa * BK + posa * 8];
                int rowb = wc * 64 + rg * 16 + m16;
                int posb = kap ^ (rowb & 7);
                bfr[rg] = *(const bf16x8*)&lB[rowb * BK + posb * 8];
            }
#pragma unroll
            for (int rg = 0; rg < 4; ++rg)
#pragma unroll
                for (int ng = 0; ng < 4; ++ng)
                    acc[rg][ng] = __builtin_amdgcn_mfma_f32_16x16x32_bf16(
                        af[rg], bfr[ng], acc[rg][ng], 0, 0, 0);
        }
    }

    float nxv[16];
#pragma unroll
    for (int rg = 0; rg < 4; ++rg)
#pragma unroll
        for (int rr = 0; rr < 4; ++rr)
            nxv[rg * 4 + rr] = nX[i0 + wr * 64 + rg * 16 + q * 4 + rr];
    float nyv[4];
#pragma unroll
    for (int ng = 0; ng < 4; ++ng)
        nyv[ng] = nY[j0 + wc * 64 + ng * 16 + m16];

    uint_t* tileBase = dbuf + (size_t)slot * 8192;
    float local;
    if (z < 2 && bi == bj)
        local = epilogue_store<true>(acc, nxv, nyv, wr, wc, q, m16, tid, tileBase);
    else
        local = epilogue_store<false>(acc, nxv, nyv, wr, wc, q, m16, tid, tileBase);

#pragma unroll
    for (int off = 32; off > 0; off >>= 1) local += __shfl_xor(local, off, 64);
    if (lane == 0) red[w] = local;
    __syncthreads();
    if (tid == 0) {
        float bs = red[0] + red[1] + red[2] + red[3];
        float c1 = (z < 2 && bi != bj) ? 2.0f : 1.0f;    // mean coefficient
        partialArr[slot] = c1 * bs;                       // plain store, no atomic
    }
}

// -------- reduce1: per-z distance sums from tile partials (1 block) --------

__global__ __launch_bounds__(256) void mmd_reduce1(
        const float* __restrict__ partialArr, double* __restrict__ sums) {
    const int tid = threadIdx.x;
    double a0 = 0.0, a1 = 0.0, a2 = 0.0;
    for (int s = tid; s < NSLOT; s += 256) {
        double v = (double)partialArr[s];
        if (s < 528) a0 += v; else if (s < 1056) a1 += v; else a2 += v;
    }
    const int lane = tid & 63, w = tid >> 6;
#pragma unroll
    for (int off = 32; off > 0; off >>= 1) {
        a0 += __shfl_xor(a0, off, 64);
        a1 += __shfl_xor(a1, off, 64);
        a2 += __shfl_xor(a2, off, 64);
    }
    __shared__ double r[4][3];
    if (lane == 0) { r[w][0] = a0; r[w][1] = a1; r[w][2] = a2; }
    __syncthreads();
    if (tid == 0) {
        sums[0] = r[0][0] + r[1][0] + r[2][0] + r[3][0];
        sums[1] = r[0][1] + r[1][1] + r[2][1] + r[3][1];
        sums[2] = r[0][2] + r[1][2] + r[2][2] + r[3][2];
    }
}

// -------- pass 2: elementwise exp-sum over stored d -> tile partial --------

__global__ __launch_bounds__(256) void mmd_pass2(
        const uint_t* __restrict__ dbuf, const double* __restrict__ sums,
        float* __restrict__ partialArr) {
    const int tid = threadIdx.x;
    const int slot = blockIdx.x;
    const int lane = tid & 63;
    const int w = tid >> 6;
    int z, bi, bj;
    decode_slot(slot, z, bi, bj);
    double mz = sums[z] * (1.0 / 16777216.0);     // mean over 4096^2
    float nhb = (float)(-1.4426950408889634 / (4.0 * mz));  // alpha=2 exponent scale
    float coef = (z == 2) ? -2.0f : ((bi != bj) ? 2.0f : 1.0f);
    const uint_t* base = dbuf + (size_t)slot * 8192;

    float local = 0.0f;
#pragma unroll
    for (int it = 0; it < 8; ++it) {
        uint4 v = ((const uint4*)base)[it * 256 + tid];
        uint_t arr[4] = {v.x, v.y, v.z, v.w};
#pragma unroll
        for (int j = 0; j < 4; ++j) {
            h2 p = __builtin_bit_cast(h2, arr[j]);
#pragma unroll
            for (int h = 0; h < 2; ++h) {
                float d = (float)p[h];
                // sum over alphas {1/8,1/4,1/2,1,2}: u^16+u^8+u^4+u^2+u, u=2^(d*nhb)
                float u = fast_exp2(d * nhb);
                float u2 = u * u;
                float u4 = u2 * u2;
                float u8 = u4 * u4;
                float u16 = u8 * u8;
                local += (u + u2) + (u4 + u8) + u16;
            }
        }
    }

    __shared__ float red[4];
#pragma unroll
    for (int off = 32; off > 0; off >>= 1) local += __shfl_xor(local, off, 64);
    if (lane == 0) red[w] = local;
    __syncthreads();
    if (tid == 0) {
        float bs = red[0] + red[1] + red[2] + red[3];
        partialArr[slot] = coef * bs;                     // plain store, no atomic
    }
}

// -------- finalize: reduce tile partials -> loss (1 block) --------

__global__ __launch_bounds__(256) void mmd_finalize2(
        const float* __restrict__ partialArr, float* __restrict__ out) {
    const int tid = threadIdx.x;
    double acc = 0.0;
    for (int s = tid; s < NSLOT; s += 256) acc += (double)partialArr[s];
    const int lane = tid & 63, w = tid >> 6;
#pragma unroll
    for (int off = 32; off > 0; off >>= 1) acc += __shfl_xor(acc, off, 64);
    __shared__ double r[4];
    if (lane == 0) r[w] = acc;
    __syncthreads();
    if (tid == 0) {
        double S = r[0] + r[1] + r[2] + r[3];
        double l = sqrt(S / ((double)BN * (double)(BN - 1)));
        float f = (float)l;
        if (!(f == f)) f = 0.0f;
        out[0] = f;
    }
}

// -------- fallback path (ws too small for the d-buffer): two-GEMM w/ atomics --------

template <int PASS>
__global__ __launch_bounds__(256) void mmd_gemm(
        const ushort_t* __restrict__ xsb, const ushort_t* __restrict__ xtb,
        const float* __restrict__ norms, double* __restrict__ sums) {
    const int z = blockIdx.z;
    const int bi = blockIdx.y;
    const int bj = blockIdx.x;
    if (z < 2 && bj < bi) return;

    const ushort_t* X = (z == 1) ? xtb : xsb;
    const ushort_t* Y = (z == 0) ? xsb : xtb;
    const float* nX = norms + ((z == 1) ? BN : 0);
    const float* nY = norms + ((z == 0) ? 0 : BN);

    const int tid = threadIdx.x;
    const int lane = tid & 63;
    const int w = tid >> 6;
    const int wr = w >> 1;
    const int wc = w & 1;
    const int m16 = lane & 15;
    const int q = lane >> 4;

    const int i0 = bi * TILE;
    const int j0 = bj * TILE;

    __shared__ ushort_t lA[TILE * BK];
    __shared__ ushort_t lB[TILE * BK];
    __shared__ float red[4];

    float nhb = 0.0f;
    if (PASS == 2) {
        double mz = sums[z] / ((double)BN * (double)BN);
        nhb = (float)(-1.4426950408889634 / (4.0 * mz));
    }

    f32x4 acc[4][4] = {};

#pragma unroll
    for (int kk = 0; kk < KD; kk += BK) {
        __syncthreads();
#pragma unroll
        for (int t = 0; t < 4; ++t) {
            int rowblk = w * 4 + t;
            int r = rowblk * 8 + (lane >> 3);
            int cch = lane & 7;
            int gch = cch ^ (r & 7);
            const ushort_t* gA = X + (size_t)(i0 + r) * KD + (kk + gch * 8);
            const ushort_t* gB = Y + (size_t)(j0 + r) * KD + (kk + gch * 8);
            async_load16(gA, (char*)lA + rowblk * 1024);
            async_load16(gB, (char*)lB + rowblk * 1024);
        }
        __syncthreads();

#pragma unroll
        for (int ks = 0; ks < 2; ++ks) {
            bf16x8 af[4], bfr[4];
            int kap = ks * 4 + q;
#pragma unroll
            for (int rg = 0; rg < 4; ++rg) {
                int rowa = wr * 64 + rg * 16 + m16;
                int posa = kap ^ (rowa & 7);
                af[rg] = *(const bf16x8*)&lA[rowa * BK + posa * 8];
                int rowb = wc * 64 + rg * 16 + m16;
                int posb = kap ^ (rowb & 7);
                bfr[rg] = *(const bf16x8*)&lB[rowb * BK + posb * 8];
            }
#pragma unroll
            for (int rg = 0; rg < 4; ++rg)
#pragma unroll
                for (int ng = 0; ng < 4; ++ng)
                    acc[rg][ng] = __builtin_amdgcn_mfma_f32_16x16x32_bf16(
                        af[rg], bfr[ng], acc[rg][ng], 0, 0, 0);
        }
    }

    float nxv[16];
#pragma unroll
    for (int rg = 0; rg < 4; ++rg)
#pragma unroll
        for (int rr = 0; rr < 4; ++rr)
            nxv[rg * 4 + rr] = nX[i0 + wr * 64 + rg * 16 + q * 4 + rr];
    float nyv[4];
#pragma unroll
    for (int ng = 0; ng < 4; ++ng)
        nyv[ng] = nY[j0 + wc * 64 + ng * 16 + m16];

    float local = 0.0f;
#pragma unroll
    for (int rg = 0; rg < 4; ++rg) {
#pragma unroll
        for (int ng = 0; ng < 4; ++ng) {
#pragma unroll
            for (int rr = 0; rr < 4; ++rr) {
                int i = i0 + wr * 64 + rg * 16 + q * 4 + rr;
                int j = j0 + wc * 64 + ng * 16 + m16;
                float sq = nxv[rg * 4 + rr] + nyv[ng] - 2.0f * acc[rg][ng][rr];
                sq = fmaxf(sq, 0.0f);
                float d = fast_sqrt(sq);
                if (z < 2 && i == j) d = 0.0f;
                if (PASS == 1) {
                    local += d;
                } else {
                    float u = fast_exp2(d * nhb);
                    float u2 = u * u;
                    float u4 = u2 * u2;
                    float u8 = u4 * u4;
                    float u16 = u8 * u8;
                    local += u + u2 + u4 + u8 + u16;
                }
            }
        }
    }

#pragma unroll
    for (int off = 32; off > 0; off >>= 1) local += __shfl_xor(local, off, 64);
    if (lane == 0) red[w] = local;
    __syncthreads();
    if (tid == 0) {
        double bs = (double)red[0] + (double)red[1] + (double)red[2] + (double)red[3];
        double coef = (z < 2 && bi != bj) ? 2.0 : 1.0;
        if (PASS == 2 && z == 2) coef = -2.0;
        atomicAdd(&sums[PASS == 1 ? z : 3], coef * bs);
    }
}

__global__ void mmd_finalize(const double* __restrict__ sums, float* __restrict__ out) {
    double S = sums[3];
    double l = sqrt(S / ((double)BN * (double)(BN - 1)));
    float f = (float)l;
    if (!(f == f)) f = 0.0f;
    out[0] = f;
}

extern "C" void kernel_launch(void* const* d_in, const int* in_sizes, int n_in,
                              void* d_out, int out_size, void* d_ws, size_t ws_size,
                              hipStream_t stream) {
    const float* xs = (const float*)d_in[0];
    const float* xt = (const float*)d_in[1];
    float* out = (float*)d_out;

    char* ws = (char*)d_ws;
    double* sums = (double*)ws;                    // 4 doubles @ 0
    float* norms = (float*)(ws + 64);              // 8192 floats -> ends 32832
    float* partialArr = (float*)(ws + 32832);      // 2080 floats -> ends 41152 (pad 41216)
    ushort_t* xsb = (ushort_t*)(ws + 41216);       // 2 MB
    ushort_t* xtb = xsb + (size_t)BN * KD;         // 2 MB -> ends at 4235520
    uint_t* dbuf = (uint_t*)(ws + 4235520);        // 2080*32768 B = 68.16 MB

    size_t need_small = 4235520;
    size_t need_big = 4235520 + (size_t)NSLOT * 32768;   // 72,392,960

    if (ws_size < need_small) {
        (void)hipMemsetAsync(d_out, 0xC0, 4, stream);    // diagnostic marker
        return;
    }

    norm_cvt<<<2048, 256, 0, stream>>>(xs, xt, xsb, xtb, norms);

    if (ws_size >= need_big) {
        mmd_pass1<<<NSLOT, 256, 0, stream>>>(xsb, xtb, norms, partialArr, dbuf);
        mmd_reduce1<<<1, 256, 0, stream>>>(partialArr, sums);
        mmd_pass2<<<NSLOT, 256, 0, stream>>>(dbuf, sums, partialArr);
        mmd_finalize2<<<1, 256, 0, stream>>>(partialArr, out);
    } else {
        (void)hipMemsetAsync(d_ws, 0, 64, stream);
        dim3 g(32, 32, 3);
        mmd_gemm<1><<<g, 256, 0, stream>>>(xsb, xtb, norms, sums);
        mmd_gemm<2><<<g, 256, 0, stream>>>(xsb, xtb, norms, sums);
        mmd_finalize<<<1, 1, 0, stream>>>(sums, out);
    }
}